// Round 6
// baseline (451.524 us; speedup 1.0000x reference)
//
#include <hip/hip_runtime.h>
#include <stdint.h>

// ---------- types / helpers ----------
typedef __attribute__((ext_vector_type(8))) short bf16x8;
typedef __attribute__((ext_vector_type(4))) float f32x4;

__device__ __forceinline__ unsigned short f2bf(float f){
  unsigned u = __float_as_uint(f);
  u += 0x7FFFu + ((u >> 16) & 1u);          // round-to-nearest-even
  return (unsigned short)(u >> 16);
}
__device__ __forceinline__ float bf2f(unsigned short s){
  return __uint_as_float(((unsigned)s) << 16);
}

// LDS tile layout: [rows][64 bf16] = 128 B/row; 16B slot s of row r holds
// global slot (s ^ (r&7)).  Reads use lds_off; async writes are linear with
// pre-swizzled global source (global_load_lds requires linear LDS dest).
__device__ __forceinline__ int lds_off(int r, int b){
  return r * 128 + (b ^ ((r & 7) << 4));
}
// 256 B/row variant (128 bf16 per row) for the P tile
__device__ __forceinline__ int ldsP_off(int r, int b){
  return r * 256 + (b ^ ((r & 7) << 4));
}

__device__ __forceinline__ void cp16(const unsigned short* g, unsigned short* l){
  __builtin_amdgcn_global_load_lds(
      (const __attribute__((address_space(1))) unsigned int*)g,
      (__attribute__((address_space(3))) unsigned int*)l, 16, 0, 0);
}

// async stage: ROWS x 64 bf16 tile from rows of g at (row0, k0), swizzled source
template<int ROWS, int NT>
__device__ __forceinline__ void stage_async(unsigned short* lds, const unsigned short* g,
                                            long row0, long stride, long k0, int tid){
#pragma unroll
  for (int c = tid; c < ROWS * 8; c += NT){
    int r = c >> 3, s = c & 7;
    int ss = s ^ (r & 7);
    cp16(g + (row0 + r) * stride + k0 + ss * 8, lds + (long)(c & ~63) * 8);
  }
}

// XCD-aware bijective swizzle (nwg % 8 == 0 in all uses)
__device__ __forceinline__ int xcd_swz(int bid, int nwg){
  int q = nwg >> 3;
  return (bid & 7) * q + (bid >> 3);
}

// ---------- prep: weights -> bf16 transposed, x -> bf16, init score ----------
__global__ __launch_bounds__(256) void k_prep(const float* x, const float* Wm, const float* Wn,
    const float* Wr, const float* Wt, const float* Wrg, const float* Wlg, const float* bp,
    unsigned short* WT, unsigned short* WcatT, unsigned short* xbf, float* score){
  long id = (long)blockIdx.x * 256 + threadIdx.x;   // 0 .. 524288
  if (id < 1024L * 512){
    int n = (int)(id >> 9), k = (int)(id & 511);
    const float* W = (n < 256) ? Wm : ((n < 512) ? Wn : ((n < 768) ? Wr : Wt));
    WT[id] = f2bf(W[(long)k * 256 + (n & 255)]);
  }
  if (id < 256L * 512){
    int n = (int)(id >> 9), k = (int)(id & 511);
    WcatT[id] = f2bf(k < 256 ? Wrg[(long)k * 256 + n] : Wlg[(long)(k - 256) * 256 + n]);
  }
  if (id < 8192) score[id] = bp[0];
  // x -> bf16 (8 per thread, 4M total)
  long xe = id * 8;
  float4 v0 = *(const float4*)(x + xe);
  float4 v1 = *(const float4*)(x + xe + 4);
  unsigned short t[8] = { f2bf(v0.x), f2bf(v0.y), f2bf(v0.z), f2bf(v0.w),
                          f2bf(v1.x), f2bf(v1.y), f2bf(v1.z), f2bf(v1.w) };
  *(uint4*)(xbf + xe) = *(const uint4*)t;
}

// ---------- pass A: [xm|xn|xwr|xl] = x @ [Wm|Wn|Wr|Wt]  (M=8192,K=512,N=1024) ----------
__global__ __launch_bounds__(256, 3) void k_gemmA(const unsigned short* xbf, const unsigned short* WT,
    unsigned short* xm, unsigned short* xn, unsigned short* xwrT, unsigned short* xl){
  __shared__ unsigned short ldsA[128 * 64];
  __shared__ unsigned short ldsB[128 * 64];
  int tid = threadIdx.x, lane = tid & 63, w = tid >> 6;
  int r = lane & 15, gq = lane >> 4;
  int wi = w >> 1, wc = w & 1;
  int swz = xcd_swz(blockIdx.x, 512);
  int bm = swz & 63, bn = swz >> 6;           // 64 x 8

  f32x4 acc[4][4];
  f32x4 zero = {0.f, 0.f, 0.f, 0.f};
#pragma unroll
  for (int m = 0; m < 4; ++m)
#pragma unroll
    for (int n = 0; n < 4; ++n) acc[m][n] = zero;

  for (int k0 = 0; k0 < 512; k0 += 64){
    __syncthreads();
    stage_async<128, 256>(ldsA, xbf, (long)bm * 128, 512, k0, tid);
    stage_async<128, 256>(ldsB, WT, (long)bn * 128, 512, k0, tid);
    __syncthreads();
#pragma unroll
    for (int ks = 0; ks < 2; ++ks){
      int bb = ks * 64 + gq * 16;
      bf16x8 a[4], b[4];
#pragma unroll
      for (int m = 0; m < 4; ++m)
        a[m] = *(const bf16x8*)((const char*)ldsA + lds_off(wi * 64 + m * 16 + r, bb));
#pragma unroll
      for (int n = 0; n < 4; ++n)
        b[n] = *(const bf16x8*)((const char*)ldsB + lds_off(wc * 64 + n * 16 + r, bb));
      // swapped: row-dim = WT index (n), col-dim = x row (i)
#pragma unroll
      for (int m = 0; m < 4; ++m)
#pragma unroll
        for (int n = 0; n < 4; ++n)
          acc[m][n] = __builtin_amdgcn_mfma_f32_16x16x32_bf16(b[n], a[m], acc[m][n], 0, 0, 0);
    }
  }
#pragma unroll
  for (int m = 0; m < 4; ++m){
    int i = bm * 128 + wi * 64 + m * 16 + r;
#pragma unroll
    for (int n = 0; n < 4; ++n){
      int ng = bn * 128 + wc * 64 + n * 16 + gq * 4;
      int sector = ng >> 8, nc = ng & 255;
      unsigned short p[4] = { f2bf(acc[m][n][0]), f2bf(acc[m][n][1]),
                              f2bf(acc[m][n][2]), f2bf(acc[m][n][3]) };
      if (sector == 2){
#pragma unroll
        for (int q = 0; q < 4; ++q) xwrT[(long)(nc + q) * 8192 + i] = p[q];
      } else {
        unsigned short* dst = sector == 0 ? xm : (sector == 1 ? xn : xl);
        *(uint2*)(dst + (long)i * 256 + nc) = *(const uint2*)p;
      }
    }
  }
}

// ---------- row norms of xm / xn ----------
__global__ __launch_bounds__(256) void k_norms(const unsigned short* xm, const unsigned short* xn,
                                               float* nm, float* nn){
  int w = threadIdx.x >> 6, lane = threadIdx.x & 63;
  int row = blockIdx.x * 4 + w;               // 0 .. 16384
  const unsigned short* src = (row < 8192) ? xm : xn;
  int rr = row & 8191;
  unsigned short v[4];
  *(uint2*)v = *(const uint2*)(src + (long)rr * 256 + lane * 4);
  float s = 0.f;
#pragma unroll
  for (int t = 0; t < 4; ++t){ float f = bf2f(v[t]); s += f * f; }
#pragma unroll
  for (int o = 32; o; o >>= 1) s += __shfl_xor(s, o);
  if (lane == 0) ((row < 8192) ? nm : nn)[rr] = s;
}

// ---------- fused pass B: adj tile -> P(LDS bf16) -> {adj f32 store, acc2 += P@xwr} ----------
// grid 64*nsp (sp = bid % nsp -> same-XCD chunk when nsp==8); block 256 = 4 waves.
// Per block: bm = 128-row panel, sp = chunk of ntiles bn-tiles.  Persistent
// acc2[128][256] per block, written once to partial[sp] at the end.
__global__ __launch_bounds__(256, 2) void k_fused(
    const unsigned short* xm, const unsigned short* xn,
    const float* nm, const float* nn, const unsigned short* xwrT,
    float* adj, float* partial, int ntiles, int nsp){
  __shared__ char smem[65536];
  unsigned short* ldsA = (unsigned short*)smem;            // 16 KB [128][64]
  unsigned short* ldsB = (unsigned short*)(smem + 16384);  // 16 KB [128][64]
  unsigned short* ldsW = (unsigned short*)smem;            // 32 KB alias [256][64]
  char*           ldsP = smem + 32768;                     // 32 KB [128][128] bf16 swz

  int tid = threadIdx.x, lane = tid & 63, w = tid >> 6;
  int r = lane & 15, gq = lane >> 4;
  int wi = w >> 1, wj = w & 1;          // phase-1 wave grid 2x2 (64x64 tiles)
  int sp = blockIdx.x % nsp, bm = blockIdx.x / nsp;

  f32x4 zero = {0.f, 0.f, 0.f, 0.f};
  f32x4 acc2[4][8];                     // phase-2: wave tile 64(i) x 128(c)
#pragma unroll
  for (int m = 0; m < 4; ++m)
#pragma unroll
    for (int n = 0; n < 8; ++n) acc2[m][n] = zero;

  float nmi[4];
#pragma unroll
  for (int m = 0; m < 4; ++m) nmi[m] = nm[bm * 128 + wi * 64 + m * 16 + r];

  for (int t = 0; t < ntiles; ++t){
    int bn = sp * ntiles + t;
    f32x4 acc1[4][4];
#pragma unroll
    for (int m = 0; m < 4; ++m)
#pragma unroll
      for (int n = 0; n < 4; ++n) acc1[m][n] = zero;

    // ---- phase 1: adj tile = xm[bm] @ xn[bn]^T, K=256 ----
    for (int k0 = 0; k0 < 256; k0 += 64){
      __syncthreads();                  // prev readers of ldsA/B/W done
      stage_async<128, 256>(ldsA, xm, (long)bm * 128, 256, k0, tid);
      stage_async<128, 256>(ldsB, xn, (long)bn * 128, 256, k0, tid);
      __syncthreads();
      __builtin_amdgcn_s_setprio(1);
#pragma unroll
      for (int ks = 0; ks < 2; ++ks){
        int bb = ks * 64 + gq * 16;
        bf16x8 a[4], b[4];
#pragma unroll
        for (int m = 0; m < 4; ++m)
          a[m] = *(const bf16x8*)((const char*)ldsA + lds_off(wi * 64 + m * 16 + r, bb));
#pragma unroll
        for (int n = 0; n < 4; ++n)
          b[n] = *(const bf16x8*)((const char*)ldsB + lds_off(wj * 64 + n * 16 + r, bb));
        // swapped: C col (r) = xm row i, C row (gq*4+q) = xn row j
#pragma unroll
        for (int m = 0; m < 4; ++m)
#pragma unroll
          for (int n = 0; n < 4; ++n)
            acc1[m][n] = __builtin_amdgcn_mfma_f32_16x16x32_bf16(b[n], a[m], acc1[m][n], 0, 0, 0);
      }
      __builtin_amdgcn_s_setprio(0);
    }

    // ---- epilogue: adj values -> bf16 P tile in LDS ----
#pragma unroll
    for (int n = 0; n < 4; ++n){
      int jl0 = wj * 64 + n * 16 + gq * 4;
      int jb = bn * 128 + jl0;
      float4 nn4 = *(const float4*)(nn + jb);
      const float nnq[4] = { nn4.x, nn4.y, nn4.z, nn4.w };
#pragma unroll
      for (int m = 0; m < 4; ++m){
        int il = wi * 64 + m * 16 + r;
        int i = bm * 128 + il;
        unsigned short pv[4];
#pragma unroll
        for (int q = 0; q < 4; ++q){
          float sq = nmi[m] + nnq[q] - 2.f * acc1[m][n][q];
          float d = sqrtf(fmaxf(sq, 0.f)) * 0.5f;
          float v = (i == jb + q) ? 1.f : __expf(-d) * (1.f / 128.f);
          pv[q] = f2bf(v);
        }
        *(uint2*)(ldsP + ldsP_off(il, jl0 * 2)) = *(const uint2*)pv;
      }
    }
    __syncthreads();                    // P complete

    // ---- adj f32 store from P: full 128B-line nontemporal stores ----
#pragma unroll
    for (int o = 0; o < 16; ++o){
      int seg = o * 256 + tid;          // 4096 segs = 128 rows x 32 (4-elem) segs
      int row = seg >> 5, js = seg & 31;
      unsigned short pb[4];
      *(uint2*)pb = *(const uint2*)(ldsP + ldsP_off(row, js * 8));
      f32x4 v = { bf2f(pb[0]), bf2f(pb[1]), bf2f(pb[2]), bf2f(pb[3]) };
      long grow = (long)(bm * 128 + row) * 8192 + (long)bn * 128 + js * 4;
      __builtin_nontemporal_store(v, (f32x4*)(adj + grow));
    }

    // ---- phase 2: acc2 += P(128x128) @ xwr[bn tile] ----
    int wm2 = w >> 1, wn2 = w & 1;      // wave tile 64(i) x 128(c)
    for (int kh = 0; kh < 2; ++kh){
      __syncthreads();                  // P-readers done; ldsW free
      stage_async<256, 256>(ldsW, xwrT, 0, 8192, (long)bn * 128 + kh * 64, tid);
      __syncthreads();
      __builtin_amdgcn_s_setprio(1);
#pragma unroll
      for (int ks = 0; ks < 2; ++ks){
        bf16x8 a[4], b[8];
#pragma unroll
        for (int m = 0; m < 4; ++m)
          a[m] = *(const bf16x8*)(ldsP + ldsP_off(wm2 * 64 + m * 16 + r, kh * 128 + ks * 64 + gq * 16));
#pragma unroll
        for (int n = 0; n < 8; ++n)
          b[n] = *(const bf16x8*)((const char*)ldsW + lds_off(wn2 * 128 + n * 16 + r, ks * 64 + gq * 16));
        // swapped: C col (r) = i, C row (gq*4+q) = c
#pragma unroll
        for (int m = 0; m < 4; ++m)
#pragma unroll
          for (int n = 0; n < 8; ++n)
            acc2[m][n] = __builtin_amdgcn_mfma_f32_16x16x32_bf16(b[n], a[m], acc2[m][n], 0, 0, 0);
      }
      __builtin_amdgcn_s_setprio(0);
    }
  }

  // ---- write xr partial for this chunk ----
  int wm2 = w >> 1, wn2 = w & 1;
  float* dst = partial + (long)sp * 8192 * 256;
#pragma unroll
  for (int m = 0; m < 4; ++m){
    int i = bm * 128 + wm2 * 64 + m * 16 + r;
#pragma unroll
    for (int n = 0; n < 8; ++n){
      int c = wn2 * 128 + n * 16 + gq * 4;
      __builtin_nontemporal_store(acc2[m][n], (f32x4*)(dst + (long)i * 256 + c));
    }
  }
}

// ---------- reduce split partials -> xr (bf16) ----------
__global__ __launch_bounds__(256) void k_reduce_xr(const float* partial, unsigned short* xr, int S){
  long idx = ((long)blockIdx.x * 256 + threadIdx.x) * 4;
  f32x4 a = __builtin_nontemporal_load((const f32x4*)(partial + idx));
  for (int s = 1; s < S; ++s){
    f32x4 b = __builtin_nontemporal_load((const f32x4*)(partial + (long)s * 8192 * 256 + idx));
    a += b;
  }
  unsigned short p[4] = { f2bf(a[0]), f2bf(a[1]), f2bf(a[2]), f2bf(a[3]) };
  *(uint2*)(xr + idx) = make_uint2((unsigned)p[0] | ((unsigned)p[1] << 16),
                                   (unsigned)p[2] | ((unsigned)p[3] << 16));
}

// ---------- pass C: w = sigmoid([xr|xl]@[Wrg;Wlg] + b), feat, score ----------
__global__ __launch_bounds__(512, 2) void k_gate(const unsigned short* xr, const unsigned short* xl,
    const unsigned short* WcatT, const float* brg, const float* blg,
    const float* Wp, float* score){
  __shared__ unsigned short ldsA[128 * 64];
  __shared__ unsigned short ldsB[256 * 64];
  int tid = threadIdx.x, lane = tid & 63, w = tid >> 6;
  int r = lane & 15, gq = lane >> 4;
  int wi = w >> 2, wc = w & 3;                // 2 x 4 -> 128 x 256
  int bm = blockIdx.x;

  f32x4 acc[4][4];
  f32x4 zero = {0.f, 0.f, 0.f, 0.f};
#pragma unroll
  for (int m = 0; m < 4; ++m)
#pragma unroll
    for (int n = 0; n < 4; ++n) acc[m][n] = zero;

  for (int k0 = 0; k0 < 512; k0 += 64){
    const unsigned short* A = (k0 < 256) ? xr : xl;
    __syncthreads();
    stage_async<128, 512>(ldsA, A, (long)bm * 128, 256, k0 & 255, tid);
    stage_async<256, 512>(ldsB, WcatT, 0, 512, k0, tid);
    __syncthreads();
#pragma unroll
    for (int ks = 0; ks < 2; ++ks){
      int bb = ks * 64 + gq * 16;
      bf16x8 a[4], b[4];
#pragma unroll
      for (int m = 0; m < 4; ++m)
        a[m] = *(const bf16x8*)((const char*)ldsA + lds_off(wi * 64 + m * 16 + r, bb));
#pragma unroll
      for (int n = 0; n < 4; ++n)
        b[n] = *(const bf16x8*)((const char*)ldsB + lds_off(wc * 64 + n * 16 + r, bb));
#pragma unroll
      for (int m = 0; m < 4; ++m)
#pragma unroll
        for (int n = 0; n < 4; ++n)
          acc[m][n] = __builtin_amdgcn_mfma_f32_16x16x32_bf16(b[n], a[m], acc[m][n], 0, 0, 0);
    }
  }
#pragma unroll
  for (int m = 0; m < 4; ++m){
    int i = bm * 128 + wi * 64 + m * 16 + r;
    float part = 0.f;
#pragma unroll
    for (int n = 0; n < 4; ++n){
      int cb = wc * 64 + n * 16 + gq * 4;
      float4 b4  = *(const float4*)(brg + cb);
      float4 l4  = *(const float4*)(blg + cb);
      float4 wp4 = *(const float4*)(Wp + cb);
      unsigned short xr4[4], xl4[4];
      *(uint2*)xr4 = *(const uint2*)(xr + (long)i * 256 + cb);
      *(uint2*)xl4 = *(const uint2*)(xl + (long)i * 256 + cb);
      const float bq[4] = { b4.x, b4.y, b4.z, b4.w };
      const float lq[4] = { l4.x, l4.y, l4.z, l4.w };
      const float pq[4] = { wp4.x, wp4.y, wp4.z, wp4.w };
#pragma unroll
      for (int q = 0; q < 4; ++q){
        float arg = acc[m][n][q] + bq[q] + lq[q];
        float wv = 1.f / (1.f + __expf(-arg));
        float feat = (1.f - wv) * bf2f(xr4[q]) + wv * bf2f(xl4[q]);
        part += feat * pq[q];
      }
    }
    part += __shfl_xor(part, 16);
    part += __shfl_xor(part, 32);
    if (gq == 0) atomicAdd(score + i, part);
  }
}

// ---------- host ----------
extern "C" void kernel_launch(void* const* d_in, const int* in_sizes, int n_in,
                              void* d_out, int out_size, void* d_ws, size_t ws_size,
                              hipStream_t stream){
  const float* x   = (const float*)d_in[0];
  const float* Wm  = (const float*)d_in[1];
  const float* Wn  = (const float*)d_in[2];
  const float* Wr  = (const float*)d_in[3];
  const float* Wt  = (const float*)d_in[4];
  const float* Wrg = (const float*)d_in[5];
  const float* brg = (const float*)d_in[6];
  const float* Wlg = (const float*)d_in[7];
  const float* blg = (const float*)d_in[8];
  const float* Wp  = (const float*)d_in[9];
  const float* bp  = (const float*)d_in[10];

  float* adj   = (float*)d_out;
  float* score = adj + 8192L * 8192;

  char* wsb = (char*)d_ws;
  unsigned short* xm    = (unsigned short*)(wsb);                 // 4 MB
  unsigned short* xn    = (unsigned short*)(wsb + (4L  << 20));   // 4 MB
  unsigned short* xwrT  = (unsigned short*)(wsb + (8L  << 20));   // 4 MB [256][8192]
  unsigned short* xl    = (unsigned short*)(wsb + (12L << 20));   // 4 MB
  unsigned short* xr    = (unsigned short*)(wsb + (16L << 20));   // 4 MB
  float*          nm    = (float*)         (wsb + (20L << 20));   // 32 KB
  float*          nn    = nm + 8192;                              // 32 KB
  unsigned short* WT    = (unsigned short*)(wsb + (21L << 20));   // 1 MB [1024][512]
  unsigned short* WcatT = (unsigned short*)(wsb + (22L << 20));   // 256 KB [256][512]
  unsigned short* xbf   = (unsigned short*)(wsb + (23L << 20));   // 8 MB [8192][512]
  float*          partial = (float*)(wsb + (31L << 20));          // NSP * 8 MB

  int NSP = 1;
  size_t base = 31L << 20;
  if      (ws_size >= base + 8 * (8L << 20)) NSP = 8;
  else if (ws_size >= base + 4 * (8L << 20)) NSP = 4;
  else if (ws_size >= base + 2 * (8L << 20)) NSP = 2;

  k_prep  <<<2048, 256, 0, stream>>>(x, Wm, Wn, Wr, Wt, Wrg, Wlg, bp, WT, WcatT, xbf, score);
  k_gemmA <<<512, 256, 0, stream>>>(xbf, WT, xm, xn, xwrT, xl);
  k_norms <<<4096, 256, 0, stream>>>(xm, xn, nm, nn);
  k_fused <<<64 * NSP, 256, 0, stream>>>(xm, xn, nm, nn, xwrT, adj, partial, 64 / NSP, NSP);
  k_reduce_xr<<<2048, 256, 0, stream>>>(partial, xr, NSP);
  k_gate  <<<64, 512, 0, stream>>>(xr, xl, WcatT, brg, blg, Wp, score);
}

// Round 7
// 261.063 us; speedup vs baseline: 1.7296x; 1.7296x over previous
//
#include <hip/hip_runtime.h>
#include <stdint.h>

// ---------- types / helpers ----------
typedef __attribute__((ext_vector_type(8))) short bf16x8;
typedef __attribute__((ext_vector_type(4))) float f32x4;

__device__ __forceinline__ unsigned short f2bf(float f){
  unsigned u = __float_as_uint(f);
  u += 0x7FFFu + ((u >> 16) & 1u);          // round-to-nearest-even
  return (unsigned short)(u >> 16);
}
__device__ __forceinline__ float bf2f(unsigned short s){
  return __uint_as_float(((unsigned)s) << 16);
}

// LDS tile layout: [rows][64 bf16] = 128 B/row; 16B slot s of row r holds
// global slot (s ^ (r&7)).  Reads use lds_off; async writes are linear with
// pre-swizzled global source (global_load_lds requires linear LDS dest).
__device__ __forceinline__ int lds_off(int r, int b){
  return r * 128 + (b ^ ((r & 7) << 4));
}

__device__ __forceinline__ void cp16(const unsigned short* g, unsigned short* l){
  __builtin_amdgcn_global_load_lds(
      (const __attribute__((address_space(1))) unsigned int*)g,
      (__attribute__((address_space(3))) unsigned int*)l, 16, 0, 0);
}

// async stage: ROWS x 64 bf16 tile from rows of g at (row0, k0), swizzled source
template<int ROWS, int NT>
__device__ __forceinline__ void stage_async(unsigned short* lds, const unsigned short* g,
                                            long row0, long stride, long k0, int tid){
#pragma unroll
  for (int c = tid; c < ROWS * 8; c += NT){
    int r = c >> 3, s = c & 7;
    int ss = s ^ (r & 7);
    cp16(g + (row0 + r) * stride + k0 + ss * 8, lds + (long)(c & ~63) * 8);
  }
}

// immediate f32->bf16 stage (prologue use): 128 rows x 64 cols
template<int NT>
__device__ __forceinline__ void stage_adj(unsigned short* lds, const float* adj,
                                          long row0, long j, int tid){
#pragma unroll
  for (int u = 0; u < 1024 / NT; ++u){
    int c = tid + u * NT;
    int rr = c >> 3, s = c & 7;
    const f32x4* src = (const f32x4*)(adj + (row0 + rr) * 8192 + j + s * 8);
    f32x4 v0 = __builtin_nontemporal_load(src);
    f32x4 v1 = __builtin_nontemporal_load(src + 1);
    unsigned short tb[8] = { f2bf(v0[0]), f2bf(v0[1]), f2bf(v0[2]), f2bf(v0[3]),
                             f2bf(v1[0]), f2bf(v1[1]), f2bf(v1[2]), f2bf(v1[3]) };
    *(uint4*)((char*)lds + lds_off(rr, s * 16)) = *(const uint4*)tb;
  }
}

// XCD-aware bijective swizzle (nwg % 8 == 0 in all uses)
__device__ __forceinline__ int xcd_swz(int bid, int nwg){
  int q = nwg >> 3;
  return (bid & 7) * q + (bid >> 3);
}

// ---------- prep: weights -> bf16 transposed, x -> bf16, zero norms, init score ----------
__global__ __launch_bounds__(256) void k_prep(const float* x, const float* Wm, const float* Wn,
    const float* Wr, const float* Wt, const float* Wrg, const float* Wlg, const float* bp,
    unsigned short* WT, unsigned short* WcatT, unsigned short* xbf, float* nm, float* nn,
    float* score){
  long id = (long)blockIdx.x * 256 + threadIdx.x;   // 0 .. 524288
  if (id < 1024L * 512){
    int n = (int)(id >> 9), k = (int)(id & 511);
    const float* W = (n < 256) ? Wm : ((n < 512) ? Wn : ((n < 768) ? Wr : Wt));
    WT[id] = f2bf(W[(long)k * 256 + (n & 255)]);
  }
  if (id < 256L * 512){
    int n = (int)(id >> 9), k = (int)(id & 511);
    WcatT[id] = f2bf(k < 256 ? Wrg[(long)k * 256 + n] : Wlg[(long)(k - 256) * 256 + n]);
  }
  if (id < 8192){ score[id] = bp[0]; nm[id] = 0.f; nn[id] = 0.f; }
  // x -> bf16 (8 per thread, 4M total)
  long xe = id * 8;
  float4 v0 = *(const float4*)(x + xe);
  float4 v1 = *(const float4*)(x + xe + 4);
  unsigned short t[8] = { f2bf(v0.x), f2bf(v0.y), f2bf(v0.z), f2bf(v0.w),
                          f2bf(v1.x), f2bf(v1.y), f2bf(v1.z), f2bf(v1.w) };
  *(uint4*)(xbf + xe) = *(const uint4*)t;
}

// ---------- pass A: [xm|xn|xwr|xl] = x @ [Wm|Wn|Wr|Wt]; fused row-norm partials ----------
__global__ __launch_bounds__(256, 3) void k_gemmA(const unsigned short* xbf, const unsigned short* WT,
    unsigned short* xm, unsigned short* xn, unsigned short* xwrT, unsigned short* xl,
    float* nm, float* nn){
  __shared__ unsigned short ldsA[128 * 64];
  __shared__ unsigned short ldsB[128 * 64];
  int tid = threadIdx.x, lane = tid & 63, w = tid >> 6;
  int r = lane & 15, gq = lane >> 4;
  int wi = w >> 1, wc = w & 1;
  int swz = xcd_swz(blockIdx.x, 512);
  int bm = swz & 63, bn = swz >> 6;           // 64 x 8

  f32x4 acc[4][4];
  f32x4 zero = {0.f, 0.f, 0.f, 0.f};
#pragma unroll
  for (int m = 0; m < 4; ++m)
#pragma unroll
    for (int n = 0; n < 4; ++n) acc[m][n] = zero;

  for (int k0 = 0; k0 < 512; k0 += 64){
    __syncthreads();
    stage_async<128, 256>(ldsA, xbf, (long)bm * 128, 512, k0, tid);
    stage_async<128, 256>(ldsB, WT, (long)bn * 128, 512, k0, tid);
    __syncthreads();
#pragma unroll
    for (int ks = 0; ks < 2; ++ks){
      int bb = ks * 64 + gq * 16;
      bf16x8 a[4], b[4];
#pragma unroll
      for (int m = 0; m < 4; ++m)
        a[m] = *(const bf16x8*)((const char*)ldsA + lds_off(wi * 64 + m * 16 + r, bb));
#pragma unroll
      for (int n = 0; n < 4; ++n)
        b[n] = *(const bf16x8*)((const char*)ldsB + lds_off(wc * 64 + n * 16 + r, bb));
      // swapped: row-dim = WT index (n), col-dim = x row (i)
#pragma unroll
      for (int m = 0; m < 4; ++m)
#pragma unroll
        for (int n = 0; n < 4; ++n)
          acc[m][n] = __builtin_amdgcn_mfma_f32_16x16x32_bf16(b[n], a[m], acc[m][n], 0, 0, 0);
    }
  }
#pragma unroll
  for (int m = 0; m < 4; ++m){
    int i = bm * 128 + wi * 64 + m * 16 + r;
#pragma unroll
    for (int n = 0; n < 4; ++n){
      int ng = bn * 128 + wc * 64 + n * 16 + gq * 4;
      int sector = ng >> 8, nc = ng & 255;
      unsigned short p[4] = { f2bf(acc[m][n][0]), f2bf(acc[m][n][1]),
                              f2bf(acc[m][n][2]), f2bf(acc[m][n][3]) };
      if (sector == 2){
#pragma unroll
        for (int q = 0; q < 4; ++q) xwrT[(long)(nc + q) * 8192 + i] = p[q];
      } else {
        unsigned short* dst = sector == 0 ? xm : (sector == 1 ? xn : xl);
        *(uint2*)(dst + (long)i * 256 + nc) = *(const uint2*)p;
      }
    }
    // fused row-norm partial (xm: bn 0/1, xn: bn 2/3)
    if (bn < 4){
      float s = 0.f;
#pragma unroll
      for (int n = 0; n < 4; ++n)
#pragma unroll
        for (int q = 0; q < 4; ++q) s += acc[m][n][q] * acc[m][n][q];
      s += __shfl_xor(s, 16);
      s += __shfl_xor(s, 32);
      if (gq == 0) atomicAdd(((bn < 2) ? nm : nn) + i, s);
    }
  }
}

// ---------- pass B1: adj = f(xm @ xn^T)  (M=N=8192, K=256), 2-phase dbuf ----------
__global__ __launch_bounds__(256, 2) void k_adj(const unsigned short* xm, const unsigned short* xn,
    const float* nm, const float* nn, float* adj){
  __shared__ char smem[65536];                // [2] x (A 16K + B 16K)
  f32x4* ldsOut = (f32x4*)smem;               // epilogue alias [64][32]

  int tid = threadIdx.x, lane = tid & 63, w = tid >> 6;
  int r = lane & 15, gq = lane >> 4;
  int wi = w >> 1, wj = w & 1;
  int swz = xcd_swz(blockIdx.x, 4096);
  int bm = swz & 63, bn = swz >> 6;           // 64 x 64

  f32x4 acc1[4][4];
  f32x4 zero = {0.f, 0.f, 0.f, 0.f};
#pragma unroll
  for (int m = 0; m < 4; ++m)
#pragma unroll
    for (int n = 0; n < 4; ++n) acc1[m][n] = zero;

  // prologue: stage k0=0 into buf0
  stage_async<128, 256>((unsigned short*)smem, xm, (long)bm * 128, 256, 0, tid);
  stage_async<128, 256>((unsigned short*)(smem + 16384), xn, (long)bn * 128, 256, 0, tid);
  __syncthreads();

#pragma unroll
  for (int t = 0; t < 4; ++t){
    char* cbuf = smem + (t & 1) * 32768;
    if (t < 3){
      char* nbuf = smem + ((t + 1) & 1) * 32768;
      stage_async<128, 256>((unsigned short*)nbuf, xm, (long)bm * 128, 256, (t + 1) * 64, tid);
      stage_async<128, 256>((unsigned short*)(nbuf + 16384), xn, (long)bn * 128, 256, (t + 1) * 64, tid);
    }
    unsigned short* ldsA = (unsigned short*)cbuf;
    unsigned short* ldsB = (unsigned short*)(cbuf + 16384);
    __builtin_amdgcn_s_setprio(1);
#pragma unroll
    for (int ks = 0; ks < 2; ++ks){
      int bb = ks * 64 + gq * 16;
      bf16x8 a[4], b[4];
#pragma unroll
      for (int m = 0; m < 4; ++m)
        a[m] = *(const bf16x8*)((const char*)ldsA + lds_off(wi * 64 + m * 16 + r, bb));
#pragma unroll
      for (int n = 0; n < 4; ++n)
        b[n] = *(const bf16x8*)((const char*)ldsB + lds_off(wj * 64 + n * 16 + r, bb));
      // swapped: C col (r) = xm row i, C row (gq*4+q) = xn row j
#pragma unroll
      for (int m = 0; m < 4; ++m)
#pragma unroll
        for (int n = 0; n < 4; ++n)
          acc1[m][n] = __builtin_amdgcn_mfma_f32_16x16x32_bf16(b[n], a[m], acc1[m][n], 0, 0, 0);
    }
    __builtin_amdgcn_s_setprio(0);
    __syncthreads();                          // next buf staged; cur buf readers done
  }

  // epilogue math in-place: acc1 <- adj values
  float nmi[4];
#pragma unroll
  for (int m = 0; m < 4; ++m) nmi[m] = nm[bm * 128 + wi * 64 + m * 16 + r];
#pragma unroll
  for (int n = 0; n < 4; ++n){
    int jb = bn * 128 + wj * 64 + n * 16 + gq * 4;
    float4 nn4 = *(const float4*)(nn + jb);
    const float nnq[4] = { nn4.x, nn4.y, nn4.z, nn4.w };
#pragma unroll
    for (int m = 0; m < 4; ++m){
      int i = bm * 128 + wi * 64 + m * 16 + r;
#pragma unroll
      for (int q = 0; q < 4; ++q){
        float sq = nmi[m] + nnq[q] - 2.f * acc1[m][n][q];
        float d = sqrtf(fmaxf(sq, 0.f)) * 0.5f;
        acc1[m][n][q] = (i == jb + q) ? 1.f : __expf(-d) * (1.f / 128.f);
      }
    }
  }

  // two 64-row passes through LDS -> full-line nontemporal global stores
#pragma unroll
  for (int p = 0; p < 2; ++p){
    __syncthreads();
    if (wi == p){
#pragma unroll
      for (int m = 0; m < 4; ++m){
        int row64 = m * 16 + r;
#pragma unroll
        for (int n = 0; n < 4; ++n){
          int slot = wj * 16 + n * 4 + gq;
          ldsOut[row64 * 32 + (slot ^ (row64 & 7))] = acc1[m][n];
        }
      }
    }
    __syncthreads();
#pragma unroll
    for (int c = 0; c < 8; ++c){
      int rr = w * 16 + ((lane >> 3) << 1) + (c & 1);
      int slot = (c >> 1) * 8 + (lane & 7);
      f32x4 v = ldsOut[rr * 32 + (slot ^ (rr & 7))];
      long grow = (long)(bm * 128 + p * 64 + rr) * 8192 + bn * 128 + slot * 4;
      __builtin_nontemporal_store(v, (f32x4*)(adj + grow));
    }
  }
}

// ---------- pass B2: partial = adj @ xwr  (M=8192, K split, N=256), dbuf + T14 ----------
__global__ __launch_bounds__(512, 1) void k_xr(const float* adj,
    const unsigned short* xwrT, float* partial, int klen, int nblk){
  __shared__ char smem[98304];                // [2] x (A 16K + B 32K)
  int tid = threadIdx.x, lane = tid & 63, w = tid >> 6;
  int r = lane & 15, gq = lane >> 4;
  int wi = w >> 2, wc = w & 3;                // 2 x 4 -> 128 x 256
  int swz = xcd_swz(blockIdx.x, nblk);
  int bm = swz & 63, sp = swz >> 6;
  long j0 = (long)sp * klen;
  int nt = klen >> 6;

  f32x4 acc[4][4];
  f32x4 zero = {0.f, 0.f, 0.f, 0.f};
#pragma unroll
  for (int m = 0; m < 4; ++m)
#pragma unroll
    for (int n = 0; n < 4; ++n) acc[m][n] = zero;

  // prologue: stage t=0 into buf0
  stage_adj<512>((unsigned short*)smem, adj, (long)bm * 128, j0, tid);
  stage_async<256, 512>((unsigned short*)(smem + 16384), xwrT, 0, 8192, j0, tid);
  __syncthreads();

  for (int t = 0; t < nt; ++t){
    char* cbuf = smem + (t & 1) * 49152;
    char* nbuf = smem + ((t & 1) ^ 1) * 49152;
    bool pf = (t + 1 < nt);
    long jn = j0 + (long)(t + 1) * 64;
    // T14 issue-early: A f32 nontemporal loads into registers; B async stage
    f32x4 av0[2], av1[2];
    int rra[2], ssa[2];
    if (pf){
#pragma unroll
      for (int u = 0; u < 2; ++u){
        int c = tid + u * 512;
        rra[u] = c >> 3; ssa[u] = c & 7;
        const f32x4* src = (const f32x4*)(adj + (long)(bm * 128 + rra[u]) * 8192 + jn + ssa[u] * 8);
        av0[u] = __builtin_nontemporal_load(src);
        av1[u] = __builtin_nontemporal_load(src + 1);
      }
      stage_async<256, 512>((unsigned short*)(nbuf + 16384), xwrT, 0, 8192, jn, tid);
    }
    // compute on cbuf (hides the loads above)
    unsigned short* ldsA = (unsigned short*)cbuf;
    unsigned short* ldsB = (unsigned short*)(cbuf + 16384);
    __builtin_amdgcn_s_setprio(1);
#pragma unroll
    for (int ks = 0; ks < 2; ++ks){
      int bb = ks * 64 + gq * 16;
      bf16x8 a[4], b[4];
#pragma unroll
      for (int m = 0; m < 4; ++m)
        a[m] = *(const bf16x8*)((const char*)ldsA + lds_off(wi * 64 + m * 16 + r, bb));
#pragma unroll
      for (int n = 0; n < 4; ++n)
        b[n] = *(const bf16x8*)((const char*)ldsB + lds_off(wc * 64 + n * 16 + r, bb));
      // swapped: C col (r) = adj row i, C row (gq*4+q) = xwrT index c
#pragma unroll
      for (int m = 0; m < 4; ++m)
#pragma unroll
        for (int n = 0; n < 4; ++n)
          acc[m][n] = __builtin_amdgcn_mfma_f32_16x16x32_bf16(b[n], a[m], acc[m][n], 0, 0, 0);
    }
    __builtin_amdgcn_s_setprio(0);
    // T14 write-late: cvt + ds_write into next buf A
    if (pf){
#pragma unroll
      for (int u = 0; u < 2; ++u){
        unsigned short tb[8] = { f2bf(av0[u][0]), f2bf(av0[u][1]), f2bf(av0[u][2]), f2bf(av0[u][3]),
                                 f2bf(av1[u][0]), f2bf(av1[u][1]), f2bf(av1[u][2]), f2bf(av1[u][3]) };
        *(uint4*)(nbuf + lds_off(rra[u], ssa[u] * 16)) = *(const uint4*)tb;
      }
    }
    __syncthreads();
  }

  float* dst = partial + (long)sp * 8192 * 256;
#pragma unroll
  for (int m = 0; m < 4; ++m){
    int i = bm * 128 + wi * 64 + m * 16 + r;
#pragma unroll
    for (int n = 0; n < 4; ++n){
      int cb = wc * 64 + n * 16 + gq * 4;
      __builtin_nontemporal_store(acc[m][n], (f32x4*)(dst + (long)i * 256 + cb));
    }
  }
}

// ---------- reduce split partials -> xr (bf16) ----------
__global__ __launch_bounds__(256) void k_reduce_xr(const float* partial, unsigned short* xr, int S){
  long idx = ((long)blockIdx.x * 256 + threadIdx.x) * 4;
  f32x4 a = __builtin_nontemporal_load((const f32x4*)(partial + idx));
  for (int s = 1; s < S; ++s){
    f32x4 b = __builtin_nontemporal_load((const f32x4*)(partial + (long)s * 8192 * 256 + idx));
    a += b;
  }
  unsigned short p[4] = { f2bf(a[0]), f2bf(a[1]), f2bf(a[2]), f2bf(a[3]) };
  *(uint2*)(xr + idx) = make_uint2((unsigned)p[0] | ((unsigned)p[1] << 16),
                                   (unsigned)p[2] | ((unsigned)p[3] << 16));
}

// ---------- pass C: w = sigmoid([xr|xl]@[Wrg;Wlg] + b), feat, score ----------
__global__ __launch_bounds__(512, 2) void k_gate(const unsigned short* xr, const unsigned short* xl,
    const unsigned short* WcatT, const float* brg, const float* blg,
    const float* Wp, float* score){
  __shared__ unsigned short ldsA[128 * 64];
  __shared__ unsigned short ldsB[256 * 64];
  int tid = threadIdx.x, lane = tid & 63, w = tid >> 6;
  int r = lane & 15, gq = lane >> 4;
  int wi = w >> 2, wc = w & 3;                // 2 x 4 -> 128 x 256
  int bm = blockIdx.x;

  f32x4 acc[4][4];
  f32x4 zero = {0.f, 0.f, 0.f, 0.f};
#pragma unroll
  for (int m = 0; m < 4; ++m)
#pragma unroll
    for (int n = 0; n < 4; ++n) acc[m][n] = zero;

  for (int k0 = 0; k0 < 512; k0 += 64){
    const unsigned short* A = (k0 < 256) ? xr : xl;
    __syncthreads();
    stage_async<128, 512>(ldsA, A, (long)bm * 128, 256, k0 & 255, tid);
    stage_async<256, 512>(ldsB, WcatT, 0, 512, k0, tid);
    __syncthreads();
#pragma unroll
    for (int ks = 0; ks < 2; ++ks){
      int bb = ks * 64 + gq * 16;
      bf16x8 a[4], b[4];
#pragma unroll
      for (int m = 0; m < 4; ++m)
        a[m] = *(const bf16x8*)((const char*)ldsA + lds_off(wi * 64 + m * 16 + r, bb));
#pragma unroll
      for (int n = 0; n < 4; ++n)
        b[n] = *(const bf16x8*)((const char*)ldsB + lds_off(wc * 64 + n * 16 + r, bb));
#pragma unroll
      for (int m = 0; m < 4; ++m)
#pragma unroll
        for (int n = 0; n < 4; ++n)
          acc[m][n] = __builtin_amdgcn_mfma_f32_16x16x32_bf16(b[n], a[m], acc[m][n], 0, 0, 0);
    }
  }
#pragma unroll
  for (int m = 0; m < 4; ++m){
    int i = bm * 128 + wi * 64 + m * 16 + r;
    float part = 0.f;
#pragma unroll
    for (int n = 0; n < 4; ++n){
      int cb = wc * 64 + n * 16 + gq * 4;
      float4 b4  = *(const float4*)(brg + cb);
      float4 l4  = *(const float4*)(blg + cb);
      float4 wp4 = *(const float4*)(Wp + cb);
      unsigned short xr4[4], xl4[4];
      *(uint2*)xr4 = *(const uint2*)(xr + (long)i * 256 + cb);
      *(uint2*)xl4 = *(const uint2*)(xl + (long)i * 256 + cb);
      const float bq[4] = { b4.x, b4.y, b4.z, b4.w };
      const float lq[4] = { l4.x, l4.y, l4.z, l4.w };
      const float pq[4] = { wp4.x, wp4.y, wp4.z, wp4.w };
#pragma unroll
      for (int q = 0; q < 4; ++q){
        float arg = acc[m][n][q] + bq[q] + lq[q];
        float wv = 1.f / (1.f + __expf(-arg));
        float feat = (1.f - wv) * bf2f(xr4[q]) + wv * bf2f(xl4[q]);
        part += feat * pq[q];
      }
    }
    part += __shfl_xor(part, 16);
    part += __shfl_xor(part, 32);
    if (gq == 0) atomicAdd(score + i, part);
  }
}

// ---------- host ----------
extern "C" void kernel_launch(void* const* d_in, const int* in_sizes, int n_in,
                              void* d_out, int out_size, void* d_ws, size_t ws_size,
                              hipStream_t stream){
  const float* x   = (const float*)d_in[0];
  const float* Wm  = (const float*)d_in[1];
  const float* Wn  = (const float*)d_in[2];
  const float* Wr  = (const float*)d_in[3];
  const float* Wt  = (const float*)d_in[4];
  const float* Wrg = (const float*)d_in[5];
  const float* brg = (const float*)d_in[6];
  const float* Wlg = (const float*)d_in[7];
  const float* blg = (const float*)d_in[8];
  const float* Wp  = (const float*)d_in[9];
  const float* bp  = (const float*)d_in[10];

  float* adj   = (float*)d_out;
  float* score = adj + 8192L * 8192;

  char* wsb = (char*)d_ws;
  unsigned short* xm    = (unsigned short*)(wsb);                 // 4 MB
  unsigned short* xn    = (unsigned short*)(wsb + (4L  << 20));   // 4 MB
  unsigned short* xwrT  = (unsigned short*)(wsb + (8L  << 20));   // 4 MB [256][8192]
  unsigned short* xl    = (unsigned short*)(wsb + (12L << 20));   // 4 MB
  unsigned short* xr    = (unsigned short*)(wsb + (16L << 20));   // 4 MB
  float*          nm    = (float*)         (wsb + (20L << 20));   // 32 KB
  float*          nn    = nm + 8192;                              // 32 KB
  unsigned short* WT    = (unsigned short*)(wsb + (21L << 20));   // 1 MB [1024][512]
  unsigned short* WcatT = (unsigned short*)(wsb + (22L << 20));   // 256 KB [256][512]
  unsigned short* xbf   = (unsigned short*)(wsb + (23L << 20));   // 8 MB [8192][512]
  float*          partial = (float*)(wsb + (31L << 20));          // NS * 8 MB

  int NS = 1;
  size_t base = 31L << 20;
  if      (ws_size >= base + 4 * (8L << 20)) NS = 4;
  else if (ws_size >= base + 2 * (8L << 20)) NS = 2;

  k_prep  <<<2048, 256, 0, stream>>>(x, Wm, Wn, Wr, Wt, Wrg, Wlg, bp, WT, WcatT, xbf, nm, nn, score);
  k_gemmA <<<512, 256, 0, stream>>>(xbf, WT, xm, xn, xwrT, xl, nm, nn);
  k_adj   <<<4096, 256, 0, stream>>>(xm, xn, nm, nn, adj);
  k_xr    <<<64 * NS, 512, 0, stream>>>(adj, xwrT, partial, 8192 / NS, 64 * NS);
  k_reduce_xr<<<2048, 256, 0, stream>>>(partial, xr, NS);
  k_gate  <<<64, 512, 0, stream>>>(xr, xl, WcatT, brg, blg, Wp, score);
}